// Round 4
// baseline (997.318 us; speedup 1.0000x reference)
//
#include <hip/hip_runtime.h>
#include <math.h>

#define NSAMP 4194304
#define LAYERS 256
#define SPT 8            // samples per thread
#define NPAIR (SPT/2)    // packed fp32 pairs per thread

typedef float f32x2 __attribute__((ext_vector_type(2)));

// ws float layout (same as round 3):
// [0]=f3000  [1]=cpar  [2]=bo_fold  [3..6]=wo_fold[0..3]
// [16 + l*20 + 0..15]  W''[l][i][j] = amp * W * g / 2pi   (row-major, g=f32(freq)*30)
// [16 + l*20 + 16..19] b''[l][i]    = (g*b + c)/2pi + d*(g/2pi)*rowsum(W)
#define WS_W 16

__global__ void prep_kernel(
    const float* __restrict__ w_hidden, const float* __restrict__ b_hidden,
    const float* __restrict__ w_out,   const float* __restrict__ b_out,
    const float* __restrict__ a_param, const float* __restrict__ b_param,
    const float* __restrict__ c_param, const float* __restrict__ d_param,
    float* __restrict__ ws)
{
  const double TWO_PI = 6.283185307179586476925286766559;
  int idx = blockIdx.x * blockDim.x + threadIdx.x;
  float freqf = (float)exp((double)b_param[0]);   // f32(exp(b)) like reference
  float gf    = (float)((double)freqf * 30.0);    // f32(freq*30)
  float ampf  = (float)exp((double)a_param[0]);
  double scale = (double)gf / TWO_PI;             // revolution-unit W scale
  double dd = (double)d_param[0];
  if (idx < 4096) {
    int l = idx >> 4, r = idx & 15;
    float wv = (float)((double)w_hidden[idx] * scale * (double)ampf);
    ws[WS_W + l * 20 + r] = wv;
  } else if (idx < 5120) {
    int bi = idx - 4096;
    int l = bi >> 2, i = bi & 3;
    double rs = 0.0;
    for (int j = 0; j < 4; ++j) rs += (double)w_hidden[l*16 + i*4 + j];
    double bv = ((double)gf * (double)b_hidden[bi] + (double)c_param[0]) / TWO_PI
              + dd * scale * rs;
    ws[WS_W + l * 20 + 16 + i] = (float)bv;
  } else if (idx == 5120) {
    ws[0] = (float)((double)freqf * 3000.0);      // f3000
    ws[1] = c_param[0];
    double bo = (double)b_out[0]
              + dd * ((double)w_out[0] + (double)w_out[1] +
                      (double)w_out[2] + (double)w_out[3]);
    ws[2] = (float)bo;
    ws[3] = (float)((double)ampf * (double)w_out[0]);
    ws[4] = (float)((double)ampf * (double)w_out[1]);
    ws[5] = (float)((double)ampf * (double)w_out[2]);
    ws[6] = (float)((double)ampf * (double)w_out[3]);
  }
}

// accurate sin for the first layer (radians, |A| up to ~3e4):
// double Cody-Waite reduction + degree-13 Taylor (error << f32 ulp)
__device__ __forceinline__ float sin_first(float A) {
  double x = (double)A;
  double kd = rint(x * 0.31830988618379067154);   // 1/pi
  double r  = fma(-kd, 3.1415926535897931159979634685, x);
  r = fma(-kd, 1.2246467991473531772e-16, r);     // pi tail
  double r2 = r * r;
  double p = 1.6059043836821613e-10;
  p = fma(r2, p, -2.5052108385441718775e-8);
  p = fma(r2, p,  2.7557319223985890653e-6);
  p = fma(r2, p, -1.9841269841269841270e-4);
  p = fma(r2, p,  8.3333333333333333333e-3);
  p = fma(r2, p, -1.6666666666666666667e-1);
  double s = fma(r2 * r, p, r);
  int ki = (int)kd;
  if (ki & 1) s = -s;
  return (float)s;
}

// ---- packed fp32 inline-asm helpers (VOP3P) ----
#define PK_ADD(d, a, b) \
  asm("v_pk_add_f32 %0, %1, %2" : "=v"(d) : "v"(a), "v"(b))
#define PK_SUB(d, a, b) \
  asm("v_pk_add_f32 %0, %1, %2 neg_lo:[0,1] neg_hi:[0,1]" : "=v"(d) : "v"(a), "v"(b))
#define PK_MUL(d, a, b) \
  asm("v_pk_mul_f32 %0, %1, %2" : "=v"(d) : "v"(a), "v"(b))
// d = a*b + c, coeff c = SGPR double (payload float in LO half) broadcast to both halves
#define PK_FMA_CS(d, a, b, cs) \
  asm("v_pk_fma_f32 %0, %1, %2, %3 op_sel:[0,0,0] op_sel_hi:[1,1,0]" \
      : "=v"(d) : "v"(a), "v"(b), "s"(cs))
// z = w.lo * s + c   (w = SGPR double = 2 packed weights; broadcast LO weight)
#define PK_FMA_WB_LO(z, w2, s, c) \
  asm("v_pk_fma_f32 %0, %1, %2, %3 op_sel:[0,0,0] op_sel_hi:[0,1,1]" \
      : "=v"(z) : "s"(w2), "v"(s), "v"(c))
// z += w.lo * s
#define PK_FMA_WACC_LO(z, w2, s) \
  asm("v_pk_fma_f32 %0, %1, %2, %0 op_sel:[0,0,0] op_sel_hi:[0,1,1]" \
      : "+v"(z) : "s"(w2), "v"(s))
// z += w.hi * s
#define PK_FMA_WACC_HI(z, w2, s) \
  asm("v_pk_fma_f32 %0, %1, %2, %0 op_sel:[1,0,0] op_sel_hi:[1,1,1]" \
      : "+v"(z) : "s"(w2), "v"(s))

template <typename T, typename F>
constexpr T bc(F f) { return __builtin_bit_cast(T, f); }
// pack a float into the LO half of a double (bit container for SGPR pair)
constexpr double PKC(float f) {
  return bc<double>((unsigned long long)bc<unsigned int>(f));
}

// packed sin(2*pi*z), |z| < 2^21: magic-number rint + odd deg-15 Taylor
// coefficients (-1)^k (2pi)^(2k+1)/(2k+1)!
#define PK_SIN(dst, z, magicv, c15v, C13, C11, C9, C7, C5, C3, C1)  \
  {                                                                 \
    f32x2 t_, u_, r_, r2_, p_;                                      \
    PK_ADD(t_, z, magicv);                                          \
    PK_SUB(u_, t_, magicv);      /* u = rint(z) */                  \
    PK_SUB(r_, z, u_);           /* r in [-0.5, 0.5] */             \
    PK_MUL(r2_, r_, r_);                                            \
    PK_FMA_CS(p_, r2_, c15v, C13);                                  \
    PK_FMA_CS(p_, p_, r2_, C11);                                    \
    PK_FMA_CS(p_, p_, r2_, C9);                                     \
    PK_FMA_CS(p_, p_, r2_, C7);                                     \
    PK_FMA_CS(p_, p_, r2_, C5);                                     \
    PK_FMA_CS(p_, p_, r2_, C3);                                     \
    PK_FMA_CS(p_, p_, r2_, C1);                                     \
    PK_MUL(dst, r_, p_);                                            \
  }

__global__ __launch_bounds__(256) void siren_main(
    const float* __restrict__ coords,
    const float* __restrict__ w_first, const float* __restrict__ b_first,
    const float* __restrict__ ws, float* __restrict__ out)
{
  const int tid = blockIdx.x * blockDim.x + threadIdx.x;   // 0 .. NSAMP/SPT-1
  const float f3000 = ws[0], cpar = ws[1];

  float c[SPT];
  const float4* cp4 = reinterpret_cast<const float4*>(coords) + tid * (SPT / 4);
#pragma unroll
  for (int q = 0; q < SPT / 4; ++q) {
    float4 v = cp4[q];
    c[4*q+0] = v.x; c[4*q+1] = v.y; c[4*q+2] = v.z; c[4*q+3] = v.w;
  }

  float wf[4], bf[4];
#pragma unroll
  for (int i = 0; i < 4; ++i) { wf[i] = w_first[i]; bf[i] = b_first[i]; }

  // state: sin values packed as sample-pairs, per neuron
  f32x2 sp0[NPAIR], sp1[NPAIR], sp2[NPAIR], sp3[NPAIR];
#pragma unroll
  for (int p = 0; p < NPAIR; ++p) {
    float sf[2][4];
#pragma unroll
    for (int h = 0; h < 2; ++h) {
      int s = 2 * p + h;
#pragma unroll
      for (int i = 0; i < 4; ++i) {
        // replicate reference fp32 op order exactly for the argument:
        float t = __fmul_rn(c[s], wf[i]);
        t = __fadd_rn(t, bf[i]);
        float A = __fadd_rn(__fmul_rn(f3000, t), cpar);
        sf[h][i] = sin_first(A);
      }
    }
    f32x2 v0 = { sf[0][0], sf[1][0] }; sp0[p] = v0;
    f32x2 v1 = { sf[0][1], sf[1][1] }; sp1[p] = v1;
    f32x2 v2 = { sf[0][2], sf[1][2] }; sp2[p] = v2;
    f32x2 v3 = { sf[0][3], sf[1][3] }; sp3[p] = v3;
  }

  // poly coefficients as SGPR-pair bit containers (payload in LO half)
  const double C13 = PKC( 3.8199525848482823f);
  const double C11 = PKC(-15.094642576822022f);
  const double C9  = PKC( 42.058693944897630f);
  const double C7  = PKC(-76.705859753061358f);
  const double C5  = PKC( 81.605249276075034f);
  const double C3  = PKC(-41.341702240399755f);
  const double C1  = PKC( 6.2831853071795865f);
  const f32x2 magicv = { 12582912.0f, 12582912.0f };        // 1.5 * 2^23
  const f32x2 c15v   = { -0.71812927501929344f, -0.71812927501929344f };

  const double* __restrict__ Wd = reinterpret_cast<const double*>(ws + WS_W);

  // one layer from SGPR doubles W0..W9 (W row-major pairs, then bias pairs)
#define STEP(W0,W1,W2,W3,W4,W5,W6,W7,W8,W9)                              \
  {                                                                      \
    float b0_ = bc<float>((unsigned int)(bc<unsigned long long>(W8)));   \
    float b1_ = bc<float>((unsigned int)(bc<unsigned long long>(W8)>>32));\
    float b2_ = bc<float>((unsigned int)(bc<unsigned long long>(W9)));   \
    float b3_ = bc<float>((unsigned int)(bc<unsigned long long>(W9)>>32));\
    f32x2 bs0 = { b0_, b0_ }, bs1 = { b1_, b1_ };                        \
    f32x2 bs2 = { b2_, b2_ }, bs3 = { b3_, b3_ };                        \
    _Pragma("unroll")                                                    \
    for (int p = 0; p < NPAIR; ++p) {                                    \
      f32x2 z0, z1, z2, z3;                                              \
      PK_FMA_WB_LO (z0, W0, sp0[p], bs0);                                \
      PK_FMA_WACC_HI(z0, W0, sp1[p]);                                    \
      PK_FMA_WACC_LO(z0, W1, sp2[p]);                                    \
      PK_FMA_WACC_HI(z0, W1, sp3[p]);                                    \
      PK_FMA_WB_LO (z1, W2, sp0[p], bs1);                                \
      PK_FMA_WACC_HI(z1, W2, sp1[p]);                                    \
      PK_FMA_WACC_LO(z1, W3, sp2[p]);                                    \
      PK_FMA_WACC_HI(z1, W3, sp3[p]);                                    \
      PK_FMA_WB_LO (z2, W4, sp0[p], bs2);                                \
      PK_FMA_WACC_HI(z2, W4, sp1[p]);                                    \
      PK_FMA_WACC_LO(z2, W5, sp2[p]);                                    \
      PK_FMA_WACC_HI(z2, W5, sp3[p]);                                    \
      PK_FMA_WB_LO (z3, W6, sp0[p], bs3);                                \
      PK_FMA_WACC_HI(z3, W6, sp1[p]);                                    \
      PK_FMA_WACC_LO(z3, W7, sp2[p]);                                    \
      PK_FMA_WACC_HI(z3, W7, sp3[p]);                                    \
      PK_SIN(sp0[p], z0, magicv, c15v, C13, C11, C9, C7, C5, C3, C1);    \
      PK_SIN(sp1[p], z1, magicv, c15v, C13, C11, C9, C7, C5, C3, C1);    \
      PK_SIN(sp2[p], z2, magicv, c15v, C13, C11, C9, C7, C5, C3, C1);    \
      PK_SIN(sp3[p], z3, magicv, c15v, C13, C11, C9, C7, C5, C3, C1);    \
    }                                                                    \
  }

#define LOADW(P, l)                                                      \
  P##0 = Wd[(l)*10+0]; P##1 = Wd[(l)*10+1]; P##2 = Wd[(l)*10+2];         \
  P##3 = Wd[(l)*10+3]; P##4 = Wd[(l)*10+4]; P##5 = Wd[(l)*10+5];         \
  P##6 = Wd[(l)*10+6]; P##7 = Wd[(l)*10+7]; P##8 = Wd[(l)*10+8];         \
  P##9 = Wd[(l)*10+9];

  double wA0,wA1,wA2,wA3,wA4,wA5,wA6,wA7,wA8,wA9;
  double wB0,wB1,wB2,wB3,wB4,wB5,wB6,wB7,wB8,wB9;
  LOADW(wA, 0)

  for (int l = 0; l < LAYERS; l += 2) {
    LOADW(wB, l + 1)
    STEP(wA0,wA1,wA2,wA3,wA4,wA5,wA6,wA7,wA8,wA9)     // layer l
    if (l + 2 < LAYERS) { LOADW(wA, l + 2) }
    STEP(wB0,wB1,wB2,wB3,wB4,wB5,wB6,wB7,wB8,wB9)     // layer l+1
  }
#undef STEP
#undef LOADW

  const float wo0 = ws[3], wo1 = ws[4], wo2 = ws[5], wo3 = ws[6], bo = ws[2];
  float o[SPT];
#pragma unroll
  for (int p = 0; p < NPAIR; ++p) {
#pragma unroll
    for (int h = 0; h < 2; ++h) {
      float acc = fmaf(h ? sp0[p].y : sp0[p].x, wo0, bo);
      acc = fmaf(h ? sp1[p].y : sp1[p].x, wo1, acc);
      acc = fmaf(h ? sp2[p].y : sp2[p].x, wo2, acc);
      acc = fmaf(h ? sp3[p].y : sp3[p].x, wo3, acc);
      o[2*p+h] = acc;
    }
  }
  float4* op4 = reinterpret_cast<float4*>(out) + tid * (SPT / 4);
  float4 v0 = { o[0], o[1], o[2], o[3] };
  float4 v1 = { o[4], o[5], o[6], o[7] };
  op4[0] = v0;
  op4[1] = v1;
}

extern "C" void kernel_launch(void* const* d_in, const int* in_sizes, int n_in,
                              void* d_out, int out_size, void* d_ws, size_t ws_size,
                              hipStream_t stream) {
  const float* coords   = (const float*)d_in[0];
  const float* w_first  = (const float*)d_in[1];
  const float* b_first  = (const float*)d_in[2];
  const float* w_hidden = (const float*)d_in[3];
  const float* b_hidden = (const float*)d_in[4];
  const float* w_out    = (const float*)d_in[5];
  const float* b_out    = (const float*)d_in[6];
  const float* a_param  = (const float*)d_in[7];
  const float* b_param  = (const float*)d_in[8];
  const float* c_param  = (const float*)d_in[9];
  const float* d_param  = (const float*)d_in[10];
  float* ws   = (float*)d_ws;
  float* outp = (float*)d_out;

  prep_kernel<<<21, 256, 0, stream>>>(w_hidden, b_hidden, w_out, b_out,
                                      a_param, b_param, c_param, d_param, ws);

  const int threads = NSAMP / SPT;          // 524288
  siren_main<<<threads / 256, 256, 0, stream>>>(coords, w_first, b_first, ws, outp);
}

// Round 5
// 724.328 us; speedup vs baseline: 1.3769x; 1.3769x over previous
//
#include <hip/hip_runtime.h>
#include <math.h>

#define NSAMP 4194304
#define LAYERS 256
#define SPT 8   // samples per thread

// ws float layout:
// [0]=f3000  [1]=cpar  [2]=bo_fold  [3..6]=wo_fold[0..3]
// [16 + l*20 + 0..15]  W''[l][i][j] = amp * W * g / 2pi   (g = f32(freq)*30)
// [16 + l*20 + 16..19] b''[l][i]    = (g*b + c)/2pi + d*(g/2pi)*rowsum(W)
#define WS_W 16

__global__ void prep_kernel(
    const float* __restrict__ w_hidden, const float* __restrict__ b_hidden,
    const float* __restrict__ w_out,   const float* __restrict__ b_out,
    const float* __restrict__ a_param, const float* __restrict__ b_param,
    const float* __restrict__ c_param, const float* __restrict__ d_param,
    float* __restrict__ ws)
{
  const double TWO_PI = 6.283185307179586476925286766559;
  int idx = blockIdx.x * blockDim.x + threadIdx.x;
  float freqf = (float)exp((double)b_param[0]);   // f32(exp(b)) like reference
  float gf    = (float)((double)freqf * 30.0);    // f32(freq*30)
  float ampf  = (float)exp((double)a_param[0]);
  double scale = (double)gf / TWO_PI;             // revolution-unit W scale
  double dd = (double)d_param[0];
  if (idx < 4096) {
    int l = idx >> 4, r = idx & 15;
    float wv = (float)((double)w_hidden[idx] * scale * (double)ampf);
    ws[WS_W + l * 20 + r] = wv;
  } else if (idx < 5120) {
    int bi = idx - 4096;
    int l = bi >> 2, i = bi & 3;
    double rs = 0.0;
    for (int j = 0; j < 4; ++j) rs += (double)w_hidden[l*16 + i*4 + j];
    double bv = ((double)gf * (double)b_hidden[bi] + (double)c_param[0]) / TWO_PI
              + dd * scale * rs;
    ws[WS_W + l * 20 + 16 + i] = (float)bv;
  } else if (idx == 5120) {
    ws[0] = (float)((double)freqf * 3000.0);      // f3000
    ws[1] = c_param[0];
    double bo = (double)b_out[0]
              + dd * ((double)w_out[0] + (double)w_out[1] +
                      (double)w_out[2] + (double)w_out[3]);
    ws[2] = (float)bo;
    ws[3] = (float)((double)ampf * (double)w_out[0]);
    ws[4] = (float)((double)ampf * (double)w_out[1]);
    ws[5] = (float)((double)ampf * (double)w_out[2]);
    ws[6] = (float)((double)ampf * (double)w_out[3]);
  }
}

#if defined(__has_builtin)
#if __has_builtin(__builtin_amdgcn_sinf)
#define HAVE_SINF_BUILTIN 1
#endif
#endif

// hardware sin: input in revolutions, computes sin(2*pi*x)
__device__ __forceinline__ float vsin_rev(float x) {
#ifdef HAVE_SINF_BUILTIN
  return __builtin_amdgcn_sinf(x);
#else
  float r;
  asm("v_sin_f32 %0, %1" : "=v"(r) : "v"(x));
  return r;
#endif
}

// accurate sin for the first layer (radians, |A| up to ~3e4):
// double Cody-Waite reduction + degree-13 Taylor (error << f32 ulp)
__device__ __forceinline__ float sin_first(float A) {
  double x = (double)A;
  double kd = rint(x * 0.31830988618379067154);   // 1/pi
  double r  = fma(-kd, 3.1415926535897931159979634685, x);
  r = fma(-kd, 1.2246467991473531772e-16, r);     // pi tail
  double r2 = r * r;
  double p = 1.6059043836821613e-10;
  p = fma(r2, p, -2.5052108385441718775e-8);
  p = fma(r2, p,  2.7557319223985890653e-6);
  p = fma(r2, p, -1.9841269841269841270e-4);
  p = fma(r2, p,  8.3333333333333333333e-3);
  p = fma(r2, p, -1.6666666666666666667e-1);
  double s = fma(r2 * r, p, r);
  int ki = (int)kd;
  if (ki & 1) s = -s;
  return (float)s;
}

__global__ __launch_bounds__(256) void siren_main(
    const float* __restrict__ coords,
    const float* __restrict__ w_first, const float* __restrict__ b_first,
    const float* __restrict__ ws, float* __restrict__ out)
{
  const int tid = blockIdx.x * blockDim.x + threadIdx.x;   // 0 .. NSAMP/SPT-1
  const float f3000 = ws[0], cpar = ws[1];

  float c[SPT];
  const float4* cp4 = reinterpret_cast<const float4*>(coords) + tid * (SPT / 4);
#pragma unroll
  for (int q = 0; q < SPT / 4; ++q) {
    float4 v = cp4[q];
    c[4*q+0] = v.x; c[4*q+1] = v.y; c[4*q+2] = v.z; c[4*q+3] = v.w;
  }

  float wf[4], bf[4];
#pragma unroll
  for (int i = 0; i < 4; ++i) { wf[i] = w_first[i]; bf[i] = b_first[i]; }

  // sp[sample][neuron] = raw sin values (amp/d folded into downstream weights)
  float sp[SPT][4];
#pragma unroll
  for (int s = 0; s < SPT; ++s) {
#pragma unroll
    for (int i = 0; i < 4; ++i) {
      // replicate reference fp32 op order exactly for the argument:
      float t = __fmul_rn(c[s], wf[i]);
      t = __fadd_rn(t, bf[i]);
      float A = __fadd_rn(__fmul_rn(f3000, t), cpar);
      sp[s][i] = sin_first(A);
    }
  }

  const float* __restrict__ Wb = ws + WS_W;

  // one layer: z = W''*sp + b'' (revolutions), sp = sin(2*pi*z)
#define STEP(WREG)                                                      \
  {                                                                     \
    _Pragma("unroll")                                                   \
    for (int s = 0; s < SPT; ++s) {                                     \
      float z0 = fmaf(WREG[0],  sp[s][0], WREG[16]);                    \
      z0 = fmaf(WREG[1],  sp[s][1], z0);                                \
      z0 = fmaf(WREG[2],  sp[s][2], z0);                                \
      z0 = fmaf(WREG[3],  sp[s][3], z0);                                \
      float z1 = fmaf(WREG[4],  sp[s][0], WREG[17]);                    \
      z1 = fmaf(WREG[5],  sp[s][1], z1);                                \
      z1 = fmaf(WREG[6],  sp[s][2], z1);                                \
      z1 = fmaf(WREG[7],  sp[s][3], z1);                                \
      float z2 = fmaf(WREG[8],  sp[s][0], WREG[18]);                    \
      z2 = fmaf(WREG[9],  sp[s][1], z2);                                \
      z2 = fmaf(WREG[10], sp[s][2], z2);                                \
      z2 = fmaf(WREG[11], sp[s][3], z2);                                \
      float z3 = fmaf(WREG[12], sp[s][0], WREG[19]);                    \
      z3 = fmaf(WREG[13], sp[s][1], z3);                                \
      z3 = fmaf(WREG[14], sp[s][2], z3);                                \
      z3 = fmaf(WREG[15], sp[s][3], z3);                                \
      sp[s][0] = vsin_rev(z0);                                          \
      sp[s][1] = vsin_rev(z1);                                          \
      sp[s][2] = vsin_rev(z2);                                          \
      sp[s][3] = vsin_rev(z3);                                          \
    }                                                                   \
  }

  // double-buffered weight prefetch; named buffers keep indexing static
  float wA[20], wB[20];
#pragma unroll
  for (int k = 0; k < 20; ++k) wA[k] = Wb[k];

  for (int l = 0; l < LAYERS; l += 2) {
    const float* p1 = Wb + (l + 1) * 20;
#pragma unroll
    for (int k = 0; k < 20; ++k) wB[k] = p1[k];
    STEP(wA);                                   // layer l
    if (l + 2 < LAYERS) {
      const float* p2 = Wb + (l + 2) * 20;
#pragma unroll
      for (int k = 0; k < 20; ++k) wA[k] = p2[k];
    }
    STEP(wB);                                   // layer l+1
  }
#undef STEP

  const float wo0 = ws[3], wo1 = ws[4], wo2 = ws[5], wo3 = ws[6], bo = ws[2];
  float o[SPT];
#pragma unroll
  for (int s = 0; s < SPT; ++s) {
    float acc = fmaf(sp[s][0], wo0, bo);
    acc = fmaf(sp[s][1], wo1, acc);
    acc = fmaf(sp[s][2], wo2, acc);
    acc = fmaf(sp[s][3], wo3, acc);
    o[s] = acc;
  }
  float4* op4 = reinterpret_cast<float4*>(out) + tid * (SPT / 4);
  float4 v0 = { o[0], o[1], o[2], o[3] };
  float4 v1 = { o[4], o[5], o[6], o[7] };
  op4[0] = v0;
  op4[1] = v1;
}

extern "C" void kernel_launch(void* const* d_in, const int* in_sizes, int n_in,
                              void* d_out, int out_size, void* d_ws, size_t ws_size,
                              hipStream_t stream) {
  const float* coords   = (const float*)d_in[0];
  const float* w_first  = (const float*)d_in[1];
  const float* b_first  = (const float*)d_in[2];
  const float* w_hidden = (const float*)d_in[3];
  const float* b_hidden = (const float*)d_in[4];
  const float* w_out    = (const float*)d_in[5];
  const float* b_out    = (const float*)d_in[6];
  const float* a_param  = (const float*)d_in[7];
  const float* b_param  = (const float*)d_in[8];
  const float* c_param  = (const float*)d_in[9];
  const float* d_param  = (const float*)d_in[10];
  float* ws   = (float*)d_ws;
  float* outp = (float*)d_out;

  prep_kernel<<<21, 256, 0, stream>>>(w_hidden, b_hidden, w_out, b_out,
                                      a_param, b_param, c_param, d_param, ws);

  const int threads = NSAMP / SPT;          // 524288
  siren_main<<<threads / 256, 256, 0, stream>>>(coords, w_first, b_first, ws, outp);
}